// Round 7
// baseline (304.167 us; speedup 1.0000x reference)
//
#include <hip/hip_runtime.h>

// GRU cell, B=8192, IN=H=1024, OUT=512 — bf16 MFMA pipeline.
// R13: GEMM1 merged to 4 phases/iter (1 kstep = 32 MFMA per phase).
//  Evidence: phase time ~1900cyc is a fixed boundary cost (R9->R10 barrier
//  halving: -3.5us only; k_gemm4 at half the MFMA/phase runs the same
//  per-phase time). So amortize: 128 -> 64 phases, 2x MFMA per phase.
//  Phase = {read af[8]+bf[4] (12 ds_read_b128); stage A+B of kstep+3
//  (4 gld16); s_waitcnt vmcnt(8); s_barrier; 32 MFMA}.
//  FIFO (4-slot ring, stage 3 ahead, 4 loads/phase): W@phase t retires the
//  stage issued at t-2 = slot (t+1)%4, read next phase. Prologue: stage
//  slots 0,1,2 (12 loads), vmcnt(8) retires slot0. Tail: vmcnt(4)@p1,
//  vmcnt(0)@p2, plain bar @p3. Overwrite-vs-read: stage at t targets the
//  slot last read at t-1, pre-barrier (same discipline as R10/R12).
//  VGPR: frags 48 (af8+bf4) + acc 128; budget at (512,2) = 256/wave ->
//  arch side must fit 128. R11 spilled at 64 frag regs; 48 should fit.
//  Falsifier: WRITE_SIZE >> 49 MB => spill => revert.
// GEMM2 (k_gemm4) / GEMM3 / k_prep unchanged from R12.

typedef __bf16 bf16x8 __attribute__((ext_vector_type(8)));
typedef float floatx4 __attribute__((ext_vector_type(4)));

__device__ __forceinline__ unsigned short f2bf(float f) {
  unsigned int u = __float_as_uint(f);
  u += 0x7fffu + ((u >> 16) & 1u);
  return (unsigned short)(u >> 16);
}

__device__ __forceinline__ void gld16(const void* g, void* l) {
  // async global->LDS, 16B/lane; LDS dest = wave-uniform base + lane*16
  __builtin_amdgcn_global_load_lds(
      (__attribute__((address_space(1))) void*)g,
      (__attribute__((address_space(3))) void*)l, 16, 0, 0);
}

// pack_xh (blocks 0..8191) + cvt_all (blocks 8192..14847) in one launch
__global__ void k_prep(const float* __restrict__ x, const float* __restrict__ h,
                       unsigned short* __restrict__ XH,
                       unsigned short* __restrict__ XRH,
                       const float* __restrict__ Wz, const float* __restrict__ Wr,
                       const float* __restrict__ Wh, const float* __restrict__ Wo,
                       unsigned short* __restrict__ WZR,
                       unsigned short* __restrict__ WHb,
                       unsigned short* __restrict__ WOb) {
  if (blockIdx.x < 8192) {
    int t = blockIdx.x * blockDim.x + threadIdx.x;
    int row = t >> 8;
    int c4 = (t & 255) << 2;
    float4 xv = reinterpret_cast<const float4*>(x)[t];
    float4 hv = reinterpret_cast<const float4*>(h)[t];
    ushort4 xb = make_ushort4(f2bf(xv.x), f2bf(xv.y), f2bf(xv.z), f2bf(xv.w));
    ushort4 hb = make_ushort4(f2bf(hv.x), f2bf(hv.y), f2bf(hv.z), f2bf(hv.w));
    size_t base = (size_t)row * 2048 + c4;
    *reinterpret_cast<ushort4*>(XH + base) = xb;
    *reinterpret_cast<ushort4*>(XRH + base) = xb;
    *reinterpret_cast<ushort4*>(XH + base + 1024) = hb;
    return;
  }
  int t = (blockIdx.x - 8192) * blockDim.x + threadIdx.x;  // float4 index
  const int Q = 1024 * 2048 / 4;
  const float* src;
  unsigned short* dst;
  int i;
  if (t < Q) {
    src = Wz; dst = WZR; i = t;
  } else if (t < 2 * Q) {
    src = Wr; dst = WZR + 1024 * 2048; i = t - Q;
  } else if (t < 3 * Q) {
    src = Wh; dst = WHb; i = t - 2 * Q;
  } else {
    src = Wo; dst = WOb; i = t - 3 * Q;
    if (i >= 512 * 1024 / 4) return;
  }
  float4 v = reinterpret_cast<const float4*>(src)[i];
  reinterpret_cast<ushort4*>(dst)[i] =
      make_ushort4(f2bf(v.x), f2bf(v.y), f2bf(v.z), f2bf(v.w));
}

// ---------------------------------------------------------------------------
// 4-phase-per-iter 256x256 GEMM (32 MFMA/phase): C = A * Bw^T.  EPI 0=gates.
// ---------------------------------------------------------------------------
template <int EPI>
__global__ __launch_bounds__(512, 2) void k_gemm8(
    const unsigned short* __restrict__ A, const unsigned short* __restrict__ Bw,
    int K, const float* __restrict__ bias1, const float* __restrict__ bias2,
    const float* __restrict__ hprev, float* __restrict__ Zbuf,
    unsigned short* __restrict__ XRH, float* __restrict__ outHid,
    unsigned short* __restrict__ HID, float* __restrict__ outO) {
  __shared__ __align__(16) unsigned short S[4 * 16384];  // 128 KiB

  const int tid = threadIdx.x;
  const int wave = tid >> 6;
  const int lane = tid & 63;
  const int quad = lane >> 4;
  const int l16 = lane & 15;
  const int bm = blockIdx.x;
  const int bn = blockIdx.y;
  const int wn = (wave & 3) << 6;   // 0 / 64 / 128 / 192

  // staging lane map: inverse of slot(r,c) = ((r&7)^c) + 8*(r&3) + 32*(r>>3)
  const int g_ = lane & 7;
  const int rmid = (lane >> 3) & 3;
  const int sr = ((lane >> 5) << 3) + (g_ & 4) + rmid;
  const int sck = (g_ & 3) ^ rmid;

  const unsigned short* gA =
      A + (size_t)(bm * 256 + wave * 16 + sr) * K + sck * 8;
  const unsigned short* gB =
      Bw + (size_t)(bn * 256 + wave * 16 + sr) * K + sck * 8;
  const size_t gstep = (size_t)128 * K;

  const int so = (((l16 & 7) ^ quad) << 3) + ((l16 & 3) << 6) + ((l16 >> 3) << 8);
  const int aoff = ((wave >> 2) << 3) * 512 + so;
  const int boff = 8192 + ((wave & 3) << 2) * 512 + so;

  floatx4 acc[8][4];
#pragma unroll
  for (int i = 0; i < 8; ++i)
#pragma unroll
    for (int j = 0; j < 4; ++j) acc[i][j] = floatx4{0.f, 0.f, 0.f, 0.f};

  auto stA = [&](int s, int ks) {
    unsigned short* d = S + s * 16384 + wave * 512;
    const unsigned short* g = gA + (size_t)ks * 32;
    gld16(g, d);
    gld16(g + gstep, d + 8 * 512);
  };
  auto stB = [&](int s, int ks) {
    unsigned short* d = S + s * 16384 + 8192 + wave * 512;
    const unsigned short* g = gB + (size_t)ks * 32;
    gld16(g, d);
    gld16(g + gstep, d + 8 * 512);
  };

  bf16x8 af[8], bf[4];
  auto dsAB = [&](int s) {
#pragma unroll
    for (int j = 0; j < 8; ++j)
      af[j] = *reinterpret_cast<const bf16x8*>(S + s * 16384 + aoff + j * 512);
#pragma unroll
    for (int nt = 0; nt < 4; ++nt)
      bf[nt] = *reinterpret_cast<const bf16x8*>(S + s * 16384 + boff + nt * 512);
  };
  auto mf32 = [&]() {
    __builtin_amdgcn_s_setprio(1);
#pragma unroll
    for (int mt = 0; mt < 8; ++mt)
#pragma unroll
      for (int nt = 0; nt < 4; ++nt)
        acc[mt][nt] = __builtin_amdgcn_mfma_f32_16x16x32_bf16(af[mt], bf[nt],
                                                              acc[mt][nt], 0, 0, 0);
    __builtin_amdgcn_s_setprio(0);
  };

#define BAR() asm volatile("s_barrier" ::: "memory")
#define WV8() asm volatile("s_waitcnt vmcnt(8)\n\ts_barrier" ::: "memory")
#define WV4() asm volatile("s_waitcnt vmcnt(4)\n\ts_barrier" ::: "memory")
#define WV0() asm volatile("s_waitcnt vmcnt(0)\n\ts_barrier" ::: "memory")

  // prologue: stage slots 0,1,2 (12 loads); vmcnt(8) retires slot0's pair.
  stA(0, 0); stB(0, 0);
  stA(1, 1); stB(1, 1);
  stA(2, 2); stB(2, 2);
  WV8();

  const int NK = K >> 5;   // 64 ksteps
  const int NI = NK >> 2;  // 16 iterations x 4 phases
  // Phase t: read slot t%4 (12 b128); stage slot (t+3)%4 <- kstep t+3
  // (4 gld16); vmcnt(8)+bar retires the stage issued at t-2 = the slot
  // read at t+1. Tail: vmcnt(4)@p1, vmcnt(0)@p2, plain bar @p3.
  for (int i = 0; i < NI; ++i) {
    const int ks = i << 2;
    const bool more = (i + 1 < NI);
    // p0: kstep ks+0 | stage slot3 <- ks+3 (always in range)
    dsAB(0); stA(3, ks + 3); stB(3, ks + 3);
    WV8(); mf32();
    // p1: kstep ks+1 | stage slot0 <- ks+4
    dsAB(1); if (more) { stA(0, ks + 4); stB(0, ks + 4); }
    if (more) { WV8(); } else { WV4(); }
    mf32();
    // p2: kstep ks+2 | stage slot1 <- ks+5
    dsAB(2); if (more) { stA(1, ks + 5); stB(1, ks + 5); }
    if (more) { WV8(); } else { WV0(); }
    mf32();
    // p3: kstep ks+3 | stage slot2 <- ks+6
    dsAB(3); if (more) { stA(2, ks + 6); stB(2, ks + 6); }
    if (more) { WV8(); } else { BAR(); }
    mf32();
  }
#undef BAR
#undef WV8
#undef WV4
#undef WV0

  // Epilogue. C/D layout: col = lane&15, row = quad*4 + reg.
  // nt innermost: each row's 4x64B output chunks issue contiguously.
  const int wm = (wave >> 2) << 7;
#pragma unroll
  for (int mt = 0; mt < 8; ++mt) {
#pragma unroll
    for (int r = 0; r < 4; ++r) {
      const int m = bm * 256 + wm + mt * 16 + quad * 4 + r;
#pragma unroll
      for (int nt = 0; nt < 4; ++nt) {
        const int n = bn * 256 + wn + nt * 16 + l16;
        if (EPI == 0) {
          const bool isz = (n < 1024);  // wave-uniform (wn 64-aligned)
          const int nn = isz ? n : n - 1024;
          const float bb = isz ? bias1[nn] : bias2[nn];
          float v = acc[mt][nt][r] + bb;
          float s = 1.f / (1.f + __expf(-v));
          if (isz) {
            Zbuf[(size_t)m * 1024 + nn] = s;  // fp32: no gate quantization
          } else {
            XRH[(size_t)m * 2048 + 1024 + nn] =
                f2bf(s * hprev[(size_t)m * 1024 + nn]);
          }
        } else {
          const float bb = bias1[n];
          float v = acc[mt][nt][r] + bb;
          float e = __expf(-2.f * v);
          float th = (1.f - e) / (1.f + e);
          float z = Zbuf[(size_t)m * 1024 + n];
          float hold = hprev[(size_t)m * 1024 + n];
          float hid = hold + z * (th - hold);
          outHid[(size_t)m * 1024 + n] = hid;
          HID[(size_t)m * 1024 + n] = f2bf(hid);
        }
      }
    }
  }
}

// ---------------------------------------------------------------------------
// 4-phase 256x128 GEMM for GEMM2 (candidate+combine), full 256-block grid.
// Per wave 64x64 (acc=64), 16 MFMA/phase, ring-4 slots, vmcnt(6)/phase.
// ---------------------------------------------------------------------------
__global__ __launch_bounds__(512, 2) void k_gemm4(
    const unsigned short* __restrict__ A, const unsigned short* __restrict__ Bw,
    int K, const float* __restrict__ bias1, const float* __restrict__ hprev,
    float* __restrict__ Zbuf, float* __restrict__ outHid,
    unsigned short* __restrict__ HID) {
  constexpr int SLOT = 12288;  // shorts: A 256x32 (8192) + B 128x32 (4096)
  __shared__ __align__(16) unsigned short S[4 * SLOT];  // 96 KiB

  const int tid = threadIdx.x;
  const int wave = tid >> 6;
  const int lane = tid & 63;
  const int quad = lane >> 4;
  const int l16 = lane & 15;
  const int bm = blockIdx.x;
  const int bn = blockIdx.y;
  const int wmi = wave >> 1;  // 0..3
  const int wni = wave & 1;   // 0..1
  const int wm = wmi << 6;    // 0/64/128/192
  const int wn = wni << 6;    // 0/64

  const int g_ = lane & 7;
  const int rmid = (lane >> 3) & 3;
  const int sr = ((lane >> 5) << 3) + (g_ & 4) + rmid;
  const int sck = (g_ & 3) ^ rmid;

  const unsigned short* gA =
      A + (size_t)(bm * 256 + wave * 16 + sr) * K + sck * 8;
  const unsigned short* gB =
      Bw + (size_t)(bn * 128 + wave * 16 + sr) * K + sck * 8;
  const size_t gstep = (size_t)128 * K;

  const int so = (((l16 & 7) ^ quad) << 3) + ((l16 & 3) << 6) + ((l16 >> 3) << 8);
  const int aoff = (wmi << 2) * 512 + so;
  const int boff = 8192 + (wni << 2) * 512 + so;

  floatx4 acc[4][4];
#pragma unroll
  for (int i = 0; i < 4; ++i)
#pragma unroll
    for (int j = 0; j < 4; ++j) acc[i][j] = floatx4{0.f, 0.f, 0.f, 0.f};

  auto stage = [&](int s, int ks) {
    unsigned short* d = S + s * SLOT;
    const unsigned short* ga = gA + (size_t)ks * 32;
    gld16(ga, d + wave * 512);
    gld16(ga + gstep, d + (wave + 8) * 512);
    gld16(gB + (size_t)ks * 32, d + 8192 + wave * 512);
  };

  bf16x8 af[4], bf[4];
  auto rd = [&](int s) {
    const unsigned short* base = S + s * SLOT;
#pragma unroll
    for (int t = 0; t < 4; ++t) {
      af[t] = *reinterpret_cast<const bf16x8*>(base + aoff + t * 512);
      bf[t] = *reinterpret_cast<const bf16x8*>(base + boff + t * 512);
    }
  };
  auto mf = [&]() {
    __builtin_amdgcn_s_setprio(1);
#pragma unroll
    for (int mt = 0; mt < 4; ++mt)
#pragma unroll
      for (int nt = 0; nt < 4; ++nt)
        acc[mt][nt] = __builtin_amdgcn_mfma_f32_16x16x32_bf16(af[mt], bf[nt],
                                                              acc[mt][nt], 0, 0, 0);
    __builtin_amdgcn_s_setprio(0);
  };

#define BAR() asm volatile("s_barrier" ::: "memory")
#define WV6() asm volatile("s_waitcnt vmcnt(6)\n\ts_barrier" ::: "memory")
#define WV3() asm volatile("s_waitcnt vmcnt(3)\n\ts_barrier" ::: "memory")
#define WV0() asm volatile("s_waitcnt vmcnt(0)\n\ts_barrier" ::: "memory")

  stage(0, 0);
  stage(1, 1);
  stage(2, 2);
  WV6();

  const int NK = K >> 5;   // 64 ksteps
  const int NI = NK >> 2;  // 16 iterations of 4 phases
  for (int i = 0; i < NI; ++i) {
    const int ks = i << 2;
    const bool more = (i + 1 < NI);
    rd(0); stage(3, ks + 3);
    WV6(); mf();
    rd(1); if (more) stage(0, ks + 4);
    if (more) { WV6(); } else { WV3(); }
    mf();
    rd(2); if (more) stage(1, ks + 5);
    if (more) { WV6(); } else { WV0(); }
    mf();
    rd(3); if (more) stage(2, ks + 6);
    if (more) { WV6(); } else { BAR(); }
    mf();
  }
#undef BAR
#undef WV6
#undef WV3
#undef WV0

#pragma unroll
  for (int mt = 0; mt < 4; ++mt) {
#pragma unroll
    for (int r = 0; r < 4; ++r) {
      const int m = bm * 256 + wm + mt * 16 + quad * 4 + r;
#pragma unroll
      for (int nt = 0; nt < 4; ++nt) {
        const int n = bn * 128 + wn + nt * 16 + l16;
        const float bb = bias1[n];
        float v = acc[mt][nt][r] + bb;
        float e = __expf(-2.f * v);
        float th = (1.f - e) / (1.f + e);
        float z = Zbuf[(size_t)m * 1024 + n];
        float hold = hprev[(size_t)m * 1024 + n];
        float hid = hold + z * (th - hold);
        outHid[(size_t)m * 1024 + n] = hid;
        HID[(size_t)m * 1024 + n] = f2bf(hid);
      }
    }
  }
}

// ---------------------------------------------------------------------------
// R6 2-phase kernel: GEMM3 (EPI=2, TM=64).
// ---------------------------------------------------------------------------
template <int EPI, int TM>
__global__ __launch_bounds__(256) void k_gemm(
    const unsigned short* __restrict__ A, const unsigned short* __restrict__ Bw,
    int K, const float* __restrict__ bias1, const float* __restrict__ bias2,
    const float* __restrict__ hprev, float* __restrict__ Zbuf,
    unsigned short* __restrict__ XRH, float* __restrict__ outHid,
    unsigned short* __restrict__ HID, float* __restrict__ outO) {
  constexpr int MT = TM / 32;
  constexpr int BUF = TM * 32 + 4096;
  constexpr int NLD = TM / 64 + 2;
  __shared__ __align__(16) unsigned short S[2 * BUF];

  const int tid = threadIdx.x;
  const int wave = tid >> 6;
  const int lane = tid & 63;
  const int bm = blockIdx.x;
  const int bn = blockIdx.y;
  const int wm = (wave >> 1) * (TM / 2);
  const int wn = (wave & 1) << 6;
  const int quad = lane >> 4;
  const int l16 = lane & 15;

  const int g_ = lane & 7;
  const int rmid = (lane >> 3) & 3;
  const int sr = (lane >> 5) * 8 + (g_ & 4) + rmid;
  const int sck = (g_ & 3) ^ rmid;
  const int arow0 = wave * (TM / 4);
  const int brow0 = wave * 32;
  const unsigned short* gA = A + (size_t)(bm * TM + arow0 + sr) * K + sck * 8;
  const unsigned short* gB = Bw + (size_t)(bn * 128 + brow0 + sr) * K + sck * 8;
  const size_t row16 = (size_t)16 * K;

  const int so = (((l16 & 7) ^ quad) << 3) + ((l16 & 3) << 6) + ((l16 >> 3) << 8);

  floatx4 acc[MT][4];
#pragma unroll
  for (int i = 0; i < MT; ++i)
#pragma unroll
    for (int j = 0; j < 4; ++j) acc[i][j] = floatx4{0.f, 0.f, 0.f, 0.f};

  auto stage = [&](int buf, int kk) {
    unsigned short* b = S + buf * BUF;
    const unsigned short* ga = gA + (size_t)kk * 32;
    const unsigned short* gb = gB + (size_t)kk * 32;
#pragma unroll
    for (int g = 0; g < TM / 64; ++g)
      gld16(ga + g * row16, b + (arow0 + g * 16) * 32);
#pragma unroll
    for (int g = 0; g < 2; ++g)
      gld16(gb + g * row16, b + TM * 32 + (brow0 + g * 16) * 32);
  };

  auto compute = [&](int buf) {
    const unsigned short* base = S + buf * BUF;
    bf16x8 af[MT], bfr[4];
#pragma unroll
    for (int mt = 0; mt < MT; ++mt)
      af[mt] = *reinterpret_cast<const bf16x8*>(base + ((wm + mt * 16) << 5) + so);
#pragma unroll
    for (int nt = 0; nt < 4; ++nt)
      bfr[nt] = *reinterpret_cast<const bf16x8*>(base + TM * 32 +
                                                 ((wn + nt * 16) << 5) + so);
#pragma unroll
    for (int mt = 0; mt < MT; ++mt)
#pragma unroll
      for (int nt = 0; nt < 4; ++nt)
        acc[mt][nt] = __builtin_amdgcn_mfma_f32_16x16x32_bf16(af[mt], bfr[nt],
                                                              acc[mt][nt], 0, 0, 0);
  };

  auto waitbarN = [&]() {
    if constexpr (NLD == 4)
      asm volatile("s_waitcnt vmcnt(4)\n\ts_barrier" ::: "memory");
    else
      asm volatile("s_waitcnt vmcnt(3)\n\ts_barrier" ::: "memory");
  };
  auto waitbar0 = [&]() {
    asm volatile("s_waitcnt vmcnt(0)\n\ts_barrier" ::: "memory");
  };
  auto endbar = [&]() {
    asm volatile("s_waitcnt lgkmcnt(0)\n\ts_barrier" ::: "memory");
  };

  const int NB = K >> 5;
  stage(0, 0);
  stage(1, 1);
  for (int k = 0; k < NB; k += 2) {
    waitbarN();
    compute(0);
    endbar();
    if (k + 2 < NB) stage(0, k + 2);
    if (k + 2 < NB) waitbarN(); else waitbar0();
    compute(1);
    endbar();
    if (k + 3 < NB) stage(1, k + 3);
  }

#pragma unroll
  for (int mt = 0; mt < MT; ++mt) {
#pragma unroll
    for (int r = 0; r < 4; ++r) {
      const int m = bm * TM + wm + mt * 16 + quad * 4 + r;
#pragma unroll
      for (int nt = 0; nt < 4; ++nt) {
        const int n = bn * 128 + wn + nt * 16 + l16;
        if (EPI == 0) {
          const bool isz = (n < 1024);
          const int nn = isz ? n : n - 1024;
          const float bb = isz ? bias1[nn] : bias2[nn];
          float v = acc[mt][nt][r] + bb;
          float s = 1.f / (1.f + __expf(-v));
          if (isz) {
            Zbuf[(size_t)m * 1024 + nn] = s;
          } else {
            XRH[(size_t)m * 2048 + 1024 + nn] =
                f2bf(s * hprev[(size_t)m * 1024 + nn]);
          }
        } else if (EPI == 1) {
          const float bb = bias1[n];
          float v = acc[mt][nt][r] + bb;
          float e = __expf(-2.f * v);
          float th = (1.f - e) / (1.f + e);
          float z = Zbuf[(size_t)m * 1024 + n];
          float hold = hprev[(size_t)m * 1024 + n];
          float hid = hold + z * (th - hold);
          outHid[(size_t)m * 1024 + n] = hid;
          HID[(size_t)m * 1024 + n] = f2bf(hid);
        } else {
          const float bb = bias1[n];
          outO[(size_t)m * 512 + n] = acc[mt][nt][r] + bb;
        }
      }
    }
  }
}

extern "C" void kernel_launch(void* const* d_in, const int* in_sizes, int n_in,
                              void* d_out, int out_size, void* d_ws, size_t ws_size,
                              hipStream_t stream) {
  const float* x = (const float*)d_in[0];
  const float* h = (const float*)d_in[1];
  const float* Wz = (const float*)d_in[2];
  const float* bz = (const float*)d_in[3];
  const float* Wr = (const float*)d_in[4];
  const float* br = (const float*)d_in[5];
  const float* Wh = (const float*)d_in[6];
  const float* bh = (const float*)d_in[7];
  const float* Wo = (const float*)d_in[8];
  const float* bo = (const float*)d_in[9];

  float* outO = (float*)d_out;                // [8192,512]
  float* outHid = outO + (size_t)8192 * 512;  // [8192,1024]

  char* ws = (char*)d_ws;
  const size_t MB = 1u << 20;
  unsigned short* XH = (unsigned short*)(ws + 0 * MB);    // [8192][2048] bf16
  unsigned short* XRH = (unsigned short*)(ws + 32 * MB);  // [8192][2048] bf16
  unsigned short* WZR = (unsigned short*)(ws + 64 * MB);  // [2048][2048] bf16
  unsigned short* WHb = (unsigned short*)(ws + 72 * MB);  // [1024][2048] bf16
  unsigned short* WOb = (unsigned short*)(ws + 76 * MB);  // [512][1024]  bf16
  float* Zb = (float*)(ws + 80 * MB);                     // [8192][1024] fp32
  unsigned short* HID = XH;  // XH dead after GEMM1 — reuse as bf16 hidden

  // pack + cvt fused into one launch
  k_prep<<<14848, 256, 0, stream>>>(x, h, XH, XRH, Wz, Wr, Wh, Wo, WZR, WHb,
                                    WOb);

  // GEMM 1: z|r fused (M=8192, N=2048, K=2048) — 4-phase/iter 256x256
  k_gemm8<0><<<dim3(32, 8), 512, 0, stream>>>(
      XH, WZR, 2048, bz, br, h, Zb, XRH, nullptr, nullptr, nullptr);
  // GEMM 2: candidate + combine (N=1024) — 4-phase 256x128, 256 blocks
  k_gemm4<<<dim3(32, 8), 512, 0, stream>>>(XRH, WHb, 2048, bh, h, Zb, outHid,
                                           HID);
  // GEMM 3: output projection (N=512), 2-phase TM=64, 512 blocks
  k_gemm<2, 64><<<dim3(128, 4), 256, 0, stream>>>(
      HID, WOb, 1024, bo, nullptr, nullptr, nullptr, nullptr, nullptr, nullptr,
      outO);
}